// Round 1
// baseline (808.957 us; speedup 1.0000x reference)
//
#include <hip/hip_runtime.h>
#include <stdint.h>

typedef unsigned short u16;
typedef __attribute__((ext_vector_type(8))) short short8;
typedef __attribute__((ext_vector_type(4))) float f32x4;

#define B_ 8
#define L_ 2048
#define D_ 1024

// ---------- bf16 helpers (RNE) ----------
__device__ __forceinline__ u16 f2bf(float f) {
    unsigned int u = __float_as_uint(f);
    u = u + 0x7FFFu + ((u >> 16) & 1u);
    return (u16)(u >> 16);
}
__device__ __forceinline__ float bf2f(u16 h) {
    return __uint_as_float(((unsigned int)h) << 16);
}

// ---------- fp32 -> bf16 conversion (float4 per thread) ----------
__global__ __launch_bounds__(256) void convert_kernel(const float* __restrict__ src,
                                                      u16* __restrict__ dst) {
    int i = blockIdx.x * 256 + threadIdx.x;
    float4 v = ((const float4*)src)[i];
    ushort4 o;
    o.x = f2bf(v.x); o.y = f2bf(v.y); o.z = f2bf(v.z); o.w = f2bf(v.w);
    ((ushort4*)dst)[i] = o;
}

// ---------- row-sum mask: mask[row] = (sum over D == 0.0f) ----------
__global__ __launch_bounds__(256) void rowmask_kernel(const float* __restrict__ x,
                                                      int* __restrict__ mask) {
    int row = blockIdx.x;
    int t = threadIdx.x;
    const float4* p = (const float4*)(x + (long)row * D_);
    float4 v = p[t];
    float s = v.x + v.y + v.z + v.w;
    #pragma unroll
    for (int off = 32; off; off >>= 1) s += __shfl_down(s, off);
    __shared__ float sh[4];
    if ((t & 63) == 0) sh[t >> 6] = s;
    __syncthreads();
    if (t == 0) {
        float tot = sh[0] + sh[1] + sh[2] + sh[3];
        mask[row] = (tot == 0.0f) ? 1 : 0;
    }
}

// ---------- async global->LDS 16B ----------
__device__ __forceinline__ void async_cp16(const void* g, void* l) {
    __builtin_amdgcn_global_load_lds((const __attribute__((address_space(1))) unsigned int*)g,
                                     (__attribute__((address_space(3))) unsigned int*)l,
                                     16, 0, 0);
}

// ---------- NT bf16 GEMM: C[m,n] = sum_k A[m,k]*B[n,k] (+ epilogue per MODE) ----------
// MODE 0: proj   : bf16 C = acc + bias[n]
// MODE 1: scores : bf16 C = maskk[n] ? -1e30 : acc*scale
// MODE 2: PV     : bf16 C = acc
// MODE 3: outproj: f32  C = acc + bias[n] + bf2f(resid[m,n])
#define GBM 128
#define GBN 128
#define GBK 32
template <int MODE>
__global__ __launch_bounds__(256) void gemm_nt(const u16* __restrict__ A,
                                               const u16* __restrict__ Bm,
                                               void* __restrict__ C,
                                               const float* __restrict__ bias,
                                               const u16* __restrict__ resid,
                                               const int* __restrict__ maskk,
                                               int N, int K,
                                               long strideA, long strideB, long strideC,
                                               float scale) {
    __shared__ __align__(16) u16 As[GBM * GBK];  // 8 KB
    __shared__ __align__(16) u16 Bs[GBN * GBK];  // 8 KB

    int t = threadIdx.x;
    int lane = t & 63;
    int wave = t >> 6;
    int wm = wave & 1, wn = wave >> 1;
    long m0 = (long)blockIdx.x * GBM;
    long n0 = (long)blockIdx.y * GBN;

    A += (long)blockIdx.z * strideA;
    Bm += (long)blockIdx.z * strideB;
    char* Cb = (char*)C + (long)blockIdx.z * strideC;
    const int* mk = (MODE == 1) ? (maskk + (long)blockIdx.z * N) : nullptr;

    f32x4 acc[4][4] = {};

    // staging: thread t loads 16B (8 bf16): row = t/4 (+64 second pass), kcol = (t%4)*8
    int arow = t >> 2;
    int acol = (t & 3) * 8;
    const u16* gA = A + (m0 + arow) * (long)K + acol;
    const u16* gB = Bm + (n0 + arow) * (long)K + acol;
    u16* lA = As + t * 8;
    u16* lB = Bs + t * 8;

    int mrow = wm * 64 + (lane & 15);
    int nrow = wn * 64 + (lane & 15);
    int koff = (lane >> 4) * 8;

    for (int k0 = 0; k0 < K; k0 += GBK) {
        async_cp16(gA, lA);
        async_cp16(gA + 64 * (long)K, lA + 2048);
        async_cp16(gB, lB);
        async_cp16(gB + 64 * (long)K, lB + 2048);
        gA += GBK; gB += GBK;
        __syncthreads();

        short8 af[4], bf[4];
        #pragma unroll
        for (int i = 0; i < 4; i++)
            af[i] = *(const short8*)&As[(mrow + i * 16) * GBK + koff];
        #pragma unroll
        for (int j = 0; j < 4; j++)
            bf[j] = *(const short8*)&Bs[(nrow + j * 16) * GBK + koff];
        #pragma unroll
        for (int i = 0; i < 4; i++)
            #pragma unroll
            for (int j = 0; j < 4; j++)
                acc[i][j] = __builtin_amdgcn_mfma_f32_16x16x32_bf16(af[i], bf[j], acc[i][j], 0, 0, 0);
        __syncthreads();
    }

    long crow0 = m0 + wm * 64;
    long ccol0 = n0 + wn * 64;
    #pragma unroll
    for (int i = 0; i < 4; i++) {
        #pragma unroll
        for (int j = 0; j < 4; j++) {
            long row = crow0 + i * 16 + (lane >> 4) * 4;
            long col = ccol0 + j * 16 + (lane & 15);
            #pragma unroll
            for (int r = 0; r < 4; r++) {
                float vv = acc[i][j][r];
                long rr = row + r;
                if (MODE == 0) {
                    ((u16*)Cb)[rr * N + col] = f2bf(vv + bias[col]);
                } else if (MODE == 1) {
                    float s = mk[col] ? -1e30f : vv * scale;
                    ((u16*)Cb)[rr * N + col] = f2bf(s);
                } else if (MODE == 2) {
                    ((u16*)Cb)[rr * N + col] = f2bf(vv);
                } else {
                    float x = vv + bias[col] + bf2f(resid[rr * (long)N + col]);
                    ((float*)Cb)[rr * N + col] = x;
                }
            }
        }
    }
}

// ---------- row softmax over Lk=2048 bf16 scores, query-mask folded in ----------
__global__ __launch_bounds__(256) void softmax_kernel(const u16* __restrict__ S,
                                                      u16* __restrict__ P,
                                                      const int* __restrict__ maskq) {
    long row = blockIdx.x;
    int t = threadIdx.x;
    const u16* Sr = S + row * L_;
    u16* Pr = P + row * L_;

    if (maskq[row]) {
        short8 z = {};
        *(short8*)&Pr[t * 8] = z;
        return;
    }

    short8 raw = *(const short8*)&Sr[t * 8];
    float s[8];
    #pragma unroll
    for (int e = 0; e < 8; e++) s[e] = bf2f((u16)raw[e]);

    float mx = s[0];
    #pragma unroll
    for (int e = 1; e < 8; e++) mx = fmaxf(mx, s[e]);
    #pragma unroll
    for (int off = 32; off; off >>= 1) mx = fmaxf(mx, __shfl_down(mx, off));
    __shared__ float sh[4];
    if ((t & 63) == 0) sh[t >> 6] = mx;
    __syncthreads();
    mx = fmaxf(fmaxf(sh[0], sh[1]), fmaxf(sh[2], sh[3]));
    __syncthreads();

    float e8[8], sum = 0.f;
    #pragma unroll
    for (int e = 0; e < 8; e++) { e8[e] = __expf(s[e] - mx); sum += e8[e]; }
    #pragma unroll
    for (int off = 32; off; off >>= 1) sum += __shfl_down(sum, off);
    if ((t & 63) == 0) sh[t >> 6] = sum;
    __syncthreads();
    sum = sh[0] + sh[1] + sh[2] + sh[3];
    float inv = 1.0f / sum;

    short8 o;
    #pragma unroll
    for (int e = 0; e < 8; e++) o[e] = (short)f2bf(e8[e] * inv);
    *(short8*)&Pr[t * 8] = o;
}

// ---------- bf16 transpose per batch: dst[b][d][key] = src[b][key][d] ----------
__global__ __launch_bounds__(256) void transpose_k(const u16* __restrict__ src,
                                                   u16* __restrict__ dst) {
    __shared__ u16 tile[32][34];
    long b = blockIdx.z;
    const u16* s = src + b * (long)L_ * D_;
    u16* d = dst + b * (long)L_ * D_;
    int gx = blockIdx.x * 32;  // d
    int gy = blockIdx.y * 32;  // key
    int tx = threadIdx.x, ty = threadIdx.y;
    #pragma unroll
    for (int r = 0; r < 32; r += 8)
        tile[ty + r][tx] = s[(long)(gy + ty + r) * D_ + gx + tx];
    __syncthreads();
    #pragma unroll
    for (int r = 0; r < 32; r += 8)
        d[(long)(gx + ty + r) * L_ + gy + tx] = tile[tx][ty + r];
}

// ---------- LayerNorm (no affine), eps=1e-5 ----------
__global__ __launch_bounds__(256) void layernorm_kernel(const float* __restrict__ X,
                                                        float* __restrict__ O) {
    long row = blockIdx.x;
    int t = threadIdx.x;
    float4 v = ((const float4*)(X + row * D_))[t];
    float s = v.x + v.y + v.z + v.w;
    #pragma unroll
    for (int off = 32; off; off >>= 1) s += __shfl_down(s, off);
    __shared__ float sh[4];
    if ((t & 63) == 0) sh[t >> 6] = s;
    __syncthreads();
    float mu = (sh[0] + sh[1] + sh[2] + sh[3]) * (1.0f / D_);
    __syncthreads();

    float dx = v.x - mu, dy = v.y - mu, dz = v.z - mu, dw = v.w - mu;
    float ss = dx * dx + dy * dy + dz * dz + dw * dw;
    #pragma unroll
    for (int off = 32; off; off >>= 1) ss += __shfl_down(ss, off);
    if ((t & 63) == 0) sh[t >> 6] = ss;
    __syncthreads();
    float var = (sh[0] + sh[1] + sh[2] + sh[3]) * (1.0f / D_);
    float rs = rsqrtf(var + 1e-5f);

    float4 o;
    o.x = dx * rs; o.y = dy * rs; o.z = dz * rs; o.w = dw * rs;
    ((float4*)(O + row * D_))[t] = o;
}

extern "C" void kernel_launch(void* const* d_in, const int* in_sizes, int n_in,
                              void* d_out, int out_size, void* d_ws, size_t ws_size,
                              hipStream_t stream) {
    const float* q  = (const float*)d_in[0];
    const float* k  = (const float*)d_in[1];
    const float* v  = (const float*)d_in[2];
    const float* Wq = (const float*)d_in[3];
    const float* bq = (const float*)d_in[4];
    const float* Wk = (const float*)d_in[5];
    const float* bk = (const float*)d_in[6];
    const float* Wv = (const float*)d_in[7];
    const float* bv = (const float*)d_in[8];
    const float* Wo = (const float*)d_in[9];
    const float* bo = (const float*)d_in[10];
    float* out = (float*)d_out;

    char* ws = (char*)d_ws;
    const size_t SZ = (size_t)B_ * L_ * D_ * 2;  // 33,554,432 B (one [B,L,D] bf16)

    // Region A (4*SZ): qb,kb,vb,vpb -> then S(2*SZ) | P at +2*SZ -> then O(SZ) | X at +2*SZ
    u16* qb   = (u16*)(ws + 0 * SZ);
    u16* kb   = (u16*)(ws + 1 * SZ);
    u16* vb   = (u16*)(ws + 2 * SZ);
    u16* vpb  = (u16*)(ws + 3 * SZ);
    u16* Sbuf = (u16*)(ws + 0 * SZ);       // 2*SZ bytes, alive: scores GEMM -> softmax
    u16* Pbuf = (u16*)(ws + 2 * SZ);       // 2*SZ bytes, alive: softmax -> PV GEMM
    u16* Obuf = (u16*)(ws + 0 * SZ);       // SZ bytes,  alive: PV GEMM -> outproj
    float* Xbuf = (float*)(ws + 2 * SZ);   // 2*SZ bytes, alive: outproj -> layernorm
    char* p = ws + 4 * SZ;
    u16* qpb = (u16*)p; p += SZ;           // projected q (bf16), also residual
    u16* kpb = (u16*)p; p += SZ;
    u16* vpT = (u16*)p; p += SZ;           // transposed projected v
    u16* Wqb = (u16*)p; p += (size_t)D_ * D_ * 2;
    u16* Wkb = (u16*)p; p += (size_t)D_ * D_ * 2;
    u16* Wvb = (u16*)p; p += (size_t)D_ * D_ * 2;
    u16* Wob = (u16*)p; p += (size_t)D_ * D_ * 2;
    int* maskq = (int*)p; p += (size_t)B_ * L_ * 4;
    int* maskk = (int*)p; p += (size_t)B_ * L_ * 4;

    const int nQKV4 = B_ * L_ * D_ / 4 / 256;  // 16384 blocks
    const int nW4   = D_ * D_ / 4 / 256;       // 1024 blocks

    // 1. dtype conversions + masks
    convert_kernel<<<nQKV4, 256, 0, stream>>>(q, qb);
    convert_kernel<<<nQKV4, 256, 0, stream>>>(k, kb);
    convert_kernel<<<nQKV4, 256, 0, stream>>>(v, vb);
    convert_kernel<<<nW4, 256, 0, stream>>>(Wq, Wqb);
    convert_kernel<<<nW4, 256, 0, stream>>>(Wk, Wkb);
    convert_kernel<<<nW4, 256, 0, stream>>>(Wv, Wvb);
    convert_kernel<<<nW4, 256, 0, stream>>>(Wo, Wob);
    rowmask_kernel<<<B_ * L_, 256, 0, stream>>>(q, maskq);
    rowmask_kernel<<<B_ * L_, 256, 0, stream>>>(k, maskk);

    // 2. projections: [16384,1024] x [1024,1024]^T
    dim3 gp(B_ * L_ / GBM, D_ / GBN, 1);
    gemm_nt<0><<<gp, 256, 0, stream>>>(qb, Wqb, qpb, bq, nullptr, nullptr, D_, D_, 0, 0, 0, 0.f);
    gemm_nt<0><<<gp, 256, 0, stream>>>(kb, Wkb, kpb, bk, nullptr, nullptr, D_, D_, 0, 0, 0, 0.f);
    gemm_nt<0><<<gp, 256, 0, stream>>>(vb, Wvb, vpb, bv, nullptr, nullptr, D_, D_, 0, 0, 0, 0.f);

    // 3. transpose vp for the PV GEMM
    transpose_k<<<dim3(D_ / 32, L_ / 32, B_), dim3(32, 8), 0, stream>>>(vpb, vpT);

    // 4. scores: S[b,i,j] = scale * qp_i . kp_j, key-masked
    gemm_nt<1><<<dim3(L_ / GBM, L_ / GBN, B_), 256, 0, stream>>>(
        qpb, kpb, Sbuf, nullptr, nullptr, maskk, L_, D_,
        (long)L_ * D_, (long)L_ * D_, (long)L_ * L_ * 2, 0.03125f);

    // 5. softmax rows (query-mask folded into P)
    softmax_kernel<<<B_ * L_, 256, 0, stream>>>(Sbuf, Pbuf, maskq);

    // 6. O = P @ vp  (via vpT, NT)
    gemm_nt<2><<<dim3(L_ / GBM, D_ / GBN, B_), 256, 0, stream>>>(
        Pbuf, vpT, Obuf, nullptr, nullptr, nullptr, D_, L_,
        (long)L_ * L_, (long)D_ * L_, (long)L_ * D_ * 2, 0.f);

    // 7. out-proj + bias + residual(qp)
    gemm_nt<3><<<gp, 256, 0, stream>>>(Obuf, Wob, Xbuf, bo, qpb, nullptr, D_, D_, 0, 0, 0, 0.f);

    // 8. LayerNorm -> d_out
    layernorm_kernel<<<B_ * L_, 256, 0, stream>>>(Xbuf, out);
}

// Round 2
// 711.124 us; speedup vs baseline: 1.1376x; 1.1376x over previous
//
#include <hip/hip_runtime.h>
#include <stdint.h>

typedef unsigned short u16;
typedef __attribute__((ext_vector_type(8))) short short8;
typedef __attribute__((ext_vector_type(4))) float f32x4;

#define B_ 8
#define L_ 2048
#define D_ 1024

// ---------- bf16 helpers (RNE) ----------
__device__ __forceinline__ u16 f2bf(float f) {
    unsigned int u = __float_as_uint(f);
    u = u + 0x7FFFu + ((u >> 16) & 1u);
    return (u16)(u >> 16);
}
__device__ __forceinline__ float bf2f(u16 h) {
    return __uint_as_float(((unsigned int)h) << 16);
}

// ---------- fused fp32->bf16 conversion + zero-row mask (one row per block) ----------
__global__ __launch_bounds__(256) void convmask_kernel(const float* __restrict__ x,
                                                       u16* __restrict__ xb,
                                                       int* __restrict__ mask) {
    long row = blockIdx.x;
    int t = threadIdx.x;
    float4 v = ((const float4*)(x + row * D_))[t];
    ushort4 o;
    o.x = f2bf(v.x); o.y = f2bf(v.y); o.z = f2bf(v.z); o.w = f2bf(v.w);
    ((ushort4*)(xb + row * D_))[t] = o;
    float s = v.x + v.y + v.z + v.w;
    #pragma unroll
    for (int off = 32; off; off >>= 1) s += __shfl_down(s, off);
    __shared__ float sh[4];
    if ((t & 63) == 0) sh[t >> 6] = s;
    __syncthreads();
    if (t == 0) {
        float tot = sh[0] + sh[1] + sh[2] + sh[3];
        mask[row] = (tot == 0.0f) ? 1 : 0;
    }
}

// ---------- all 4 weight matrices fp32->bf16 in one dispatch ----------
struct Ptr4 { const float* s0; const float* s1; const float* s2; const float* s3; };
__global__ __launch_bounds__(256) void convert4_kernel(Ptr4 p, u16* __restrict__ dst) {
    const float* srcs[4] = {p.s0, p.s1, p.s2, p.s3};
    const float* src = srcs[blockIdx.y];
    u16* d = dst + (size_t)blockIdx.y * D_ * D_;
    int i = blockIdx.x * 256 + threadIdx.x;
    float4 v = ((const float4*)src)[i];
    ushort4 o;
    o.x = f2bf(v.x); o.y = f2bf(v.y); o.z = f2bf(v.z); o.w = f2bf(v.w);
    ((ushort4*)d)[i] = o;
}

// ---------- block-group skip flags ----------
// blocks 0..127: qmask128 | 128..255: kmask128 | 256..383: vmask128 | 384..895: kmask32
__global__ __launch_bounds__(128) void flags_kernel(const int* __restrict__ mq,
                                                    const int* __restrict__ mk,
                                                    const int* __restrict__ mv,
                                                    int* __restrict__ q128,
                                                    int* __restrict__ k128,
                                                    int* __restrict__ v128,
                                                    int* __restrict__ k32) {
    int b = blockIdx.x, t = threadIdx.x;
    const int* src; int* dst; int g; int n;
    if (b < 128)      { src = mq; dst = q128; g = b;       n = 128; }
    else if (b < 256) { src = mk; dst = k128; g = b - 128; n = 128; }
    else if (b < 384) { src = mv; dst = v128; g = b - 256; n = 128; }
    else              { src = mk; dst = k32;  g = b - 384; n = 32;  }
    int val = (t < n) ? src[(long)g * n + t] : 1;
    __shared__ int sh;
    if (t == 0) sh = 1;
    __syncthreads();
    if (!val) sh = 0;
    __syncthreads();
    if (t == 0) dst[g] = sh;
}

// ---------- async global->LDS 16B ----------
__device__ __forceinline__ void async_cp16(const void* g, void* l) {
    __builtin_amdgcn_global_load_lds((const __attribute__((address_space(1))) unsigned int*)g,
                                     (__attribute__((address_space(3))) unsigned int*)l,
                                     16, 0, 0);
}

// ---------- NT bf16 GEMM: C[m,n] = sum_k A[m,k]*B[n,k] (+ epilogue per MODE) ----------
// MODE 0: proj   : bf16 C = acc + bias[n]
// MODE 1: scores : bf16 C = maskk[n] ? -1e30 : acc*scale
// MODE 2: PV     : bf16 C = acc
// MODE 3: outproj: f32  C = acc + bias[n] + bf2f(resid[m,n])
// LDS layout XOR-swizzled: chunk (row, kc) at slot row*4 + (kc ^ ((row>>1)&3))
// -> fragment ds_read_b128 hits each 16B granule-group exactly 2x (free).
#define GBM 128
#define GBN 128
#define GBK 32
template <int MODE>
__global__ __launch_bounds__(256) void gemm_nt(const u16* __restrict__ A,
                                               const u16* __restrict__ Bm,
                                               void* __restrict__ C,
                                               const float* __restrict__ bias,
                                               const u16* __restrict__ resid,
                                               const int* __restrict__ maskk,
                                               int N, int K,
                                               long strideA, long strideB, long strideC,
                                               float scale,
                                               const int* __restrict__ rowskip,
                                               const int* __restrict__ colskip,
                                               const int* __restrict__ kskip,
                                               int mblocks, int nblocks) {
    __shared__ __align__(16) u16 As[GBM * GBK];  // 8 KB
    __shared__ __align__(16) u16 Bs[GBN * GBK];  // 8 KB

    int t = threadIdx.x;
    int lane = t & 63;
    int wave = t >> 6;
    int wm = wave & 1, wn = wave >> 1;
    long m0 = (long)blockIdx.x * GBM;
    long n0 = (long)blockIdx.y * GBN;

    A += (long)blockIdx.z * strideA;
    Bm += (long)blockIdx.z * strideB;
    char* Cb = (char*)C + (long)blockIdx.z * strideC;
    const int* mk = (MODE == 1) ? (maskk + (long)blockIdx.z * N) : nullptr;

    bool skipK = false;
    if (rowskip && rowskip[blockIdx.z * mblocks + blockIdx.x]) skipK = true;
    if (MODE == 1 && colskip && colskip[blockIdx.z * nblocks + blockIdx.y]) skipK = true;

    f32x4 acc[4][4] = {};

    // staging: thread t -> LDS slot t (16B). Global chunk: row=t>>2, kc=(t&3)^((t>>3)&3)
    int arow = t >> 2;
    int acol = ((t & 3) ^ ((t >> 3) & 3)) * 8;
    const u16* gA = A + (m0 + arow) * (long)K + acol;
    const u16* gB = Bm + (n0 + arow) * (long)K + acol;
    u16* lA = As + t * 8;
    u16* lB = Bs + t * 8;

    int mrow = wm * 64 + (lane & 15);
    int nrow = wn * 64 + (lane & 15);
    // swizzled k-chunk offset for fragment reads (invariant across i/j since 16*i>>1 ≡ 0 mod 4)
    int sw = (((lane >> 4) ^ ((lane >> 1) & 3)) * 8);

    if (!skipK) {
        const int* ks = (MODE == 2 && kskip) ? (kskip + (long)blockIdx.z * (K >> 5)) : nullptr;
        for (int k0 = 0; k0 < K; k0 += GBK) {
            if (ks && ks[k0 >> 5]) { gA += GBK; gB += GBK; continue; }
            async_cp16(gA, lA);
            async_cp16(gA + 64 * (long)K, lA + 2048);
            async_cp16(gB, lB);
            async_cp16(gB + 64 * (long)K, lB + 2048);
            gA += GBK; gB += GBK;
            __syncthreads();

            short8 af[4], bf[4];
            #pragma unroll
            for (int i = 0; i < 4; i++)
                af[i] = *(const short8*)&As[(mrow + i * 16) * GBK + sw];
            #pragma unroll
            for (int j = 0; j < 4; j++)
                bf[j] = *(const short8*)&Bs[(nrow + j * 16) * GBK + sw];
            #pragma unroll
            for (int i = 0; i < 4; i++)
                #pragma unroll
                for (int j = 0; j < 4; j++)
                    acc[i][j] = __builtin_amdgcn_mfma_f32_16x16x32_bf16(af[i], bf[j], acc[i][j], 0, 0, 0);
            __syncthreads();
        }
    }

    long crow0 = m0 + wm * 64;
    long ccol0 = n0 + wn * 64;
    #pragma unroll
    for (int i = 0; i < 4; i++) {
        #pragma unroll
        for (int j = 0; j < 4; j++) {
            long row = crow0 + i * 16 + (lane >> 4) * 4;
            long col = ccol0 + j * 16 + (lane & 15);
            #pragma unroll
            for (int r = 0; r < 4; r++) {
                float vv = acc[i][j][r];
                long rr = row + r;
                if (MODE == 0) {
                    ((u16*)Cb)[rr * N + col] = f2bf(vv + bias[col]);
                } else if (MODE == 1) {
                    float s = mk[col] ? -1e30f : vv * scale;
                    ((u16*)Cb)[rr * N + col] = f2bf(s);
                } else if (MODE == 2) {
                    ((u16*)Cb)[rr * N + col] = f2bf(vv);
                } else {
                    float x = vv + bias[col] + bf2f(resid[rr * (long)N + col]);
                    ((float*)Cb)[rr * N + col] = x;
                }
            }
        }
    }
}

// ---------- row softmax over Lk=2048 bf16 scores, query-mask folded in ----------
__global__ __launch_bounds__(256) void softmax_kernel(const u16* __restrict__ S,
                                                      u16* __restrict__ P,
                                                      const int* __restrict__ maskq) {
    long row = blockIdx.x;
    int t = threadIdx.x;
    const u16* Sr = S + row * L_;
    u16* Pr = P + row * L_;

    if (maskq[row]) {
        short8 z = {};
        *(short8*)&Pr[t * 8] = z;
        return;
    }

    short8 raw = *(const short8*)&Sr[t * 8];
    float s[8];
    #pragma unroll
    for (int e = 0; e < 8; e++) s[e] = bf2f((u16)raw[e]);

    float mx = s[0];
    #pragma unroll
    for (int e = 1; e < 8; e++) mx = fmaxf(mx, s[e]);
    #pragma unroll
    for (int off = 32; off; off >>= 1) mx = fmaxf(mx, __shfl_down(mx, off));
    __shared__ float sh[4];
    if ((t & 63) == 0) sh[t >> 6] = mx;
    __syncthreads();
    mx = fmaxf(fmaxf(sh[0], sh[1]), fmaxf(sh[2], sh[3]));
    __syncthreads();

    float e8[8], sum = 0.f;
    #pragma unroll
    for (int e = 0; e < 8; e++) { e8[e] = __expf(s[e] - mx); sum += e8[e]; }
    #pragma unroll
    for (int off = 32; off; off >>= 1) sum += __shfl_down(sum, off);
    if ((t & 63) == 0) sh[t >> 6] = sum;
    __syncthreads();
    sum = sh[0] + sh[1] + sh[2] + sh[3];
    float inv = 1.0f / sum;

    short8 o;
    #pragma unroll
    for (int e = 0; e < 8; e++) o[e] = (short)f2bf(e8[e] * inv);
    *(short8*)&Pr[t * 8] = o;
}

// ---------- bf16 transpose per batch: dst[b][d][key] = src[b][key][d] ----------
__global__ __launch_bounds__(256) void transpose_k(const u16* __restrict__ src,
                                                   u16* __restrict__ dst) {
    __shared__ u16 tile[32][34];
    long b = blockIdx.z;
    const u16* s = src + b * (long)L_ * D_;
    u16* d = dst + b * (long)L_ * D_;
    int gx = blockIdx.x * 32;  // d
    int gy = blockIdx.y * 32;  // key
    int tx = threadIdx.x, ty = threadIdx.y;
    #pragma unroll
    for (int r = 0; r < 32; r += 8)
        tile[ty + r][tx] = s[(long)(gy + ty + r) * D_ + gx + tx];
    __syncthreads();
    #pragma unroll
    for (int r = 0; r < 32; r += 8)
        d[(long)(gx + ty + r) * L_ + gy + tx] = tile[tx][ty + r];
}

// ---------- LayerNorm (no affine), eps=1e-5 ----------
__global__ __launch_bounds__(256) void layernorm_kernel(const float* __restrict__ X,
                                                        float* __restrict__ O) {
    long row = blockIdx.x;
    int t = threadIdx.x;
    float4 v = ((const float4*)(X + row * D_))[t];
    float s = v.x + v.y + v.z + v.w;
    #pragma unroll
    for (int off = 32; off; off >>= 1) s += __shfl_down(s, off);
    __shared__ float sh[4];
    if ((t & 63) == 0) sh[t >> 6] = s;
    __syncthreads();
    float mu = (sh[0] + sh[1] + sh[2] + sh[3]) * (1.0f / D_);
    __syncthreads();

    float dx = v.x - mu, dy = v.y - mu, dz = v.z - mu, dw = v.w - mu;
    float ss = dx * dx + dy * dy + dz * dz + dw * dw;
    #pragma unroll
    for (int off = 32; off; off >>= 1) ss += __shfl_down(ss, off);
    if ((t & 63) == 0) sh[t >> 6] = ss;
    __syncthreads();
    float var = (sh[0] + sh[1] + sh[2] + sh[3]) * (1.0f / D_);
    float rs = rsqrtf(var + 1e-5f);

    float4 o;
    o.x = dx * rs; o.y = dy * rs; o.z = dz * rs; o.w = dw * rs;
    ((float4*)(O + row * D_))[t] = o;
}

extern "C" void kernel_launch(void* const* d_in, const int* in_sizes, int n_in,
                              void* d_out, int out_size, void* d_ws, size_t ws_size,
                              hipStream_t stream) {
    const float* q  = (const float*)d_in[0];
    const float* k  = (const float*)d_in[1];
    const float* v  = (const float*)d_in[2];
    const float* Wq = (const float*)d_in[3];
    const float* bq = (const float*)d_in[4];
    const float* Wk = (const float*)d_in[5];
    const float* bk = (const float*)d_in[6];
    const float* Wv = (const float*)d_in[7];
    const float* bv = (const float*)d_in[8];
    const float* Wo = (const float*)d_in[9];
    const float* bo = (const float*)d_in[10];
    float* out = (float*)d_out;

    char* ws = (char*)d_ws;
    const size_t SZ = (size_t)B_ * L_ * D_ * 2;  // 33,554,432 B (one [B,L,D] bf16)

    // Region A (4*SZ): qb,kb,vb,vpb -> then S(2*SZ) | P at +2*SZ -> then O(SZ) | X at +2*SZ
    u16* qb   = (u16*)(ws + 0 * SZ);
    u16* kb   = (u16*)(ws + 1 * SZ);
    u16* vb   = (u16*)(ws + 2 * SZ);
    u16* vpb  = (u16*)(ws + 3 * SZ);
    u16* Sbuf = (u16*)(ws + 0 * SZ);       // 2*SZ bytes, alive: scores GEMM -> softmax
    u16* Pbuf = (u16*)(ws + 2 * SZ);       // 2*SZ bytes, alive: softmax -> PV GEMM
    u16* Obuf = (u16*)(ws + 0 * SZ);       // SZ bytes,  alive: PV GEMM -> outproj
    float* Xbuf = (float*)(ws + 2 * SZ);   // 2*SZ bytes, alive: outproj -> layernorm
    char* p = ws + 4 * SZ;
    u16* qpb = (u16*)p; p += SZ;           // projected q (bf16), also residual
    u16* kpb = (u16*)p; p += SZ;
    u16* vpT = (u16*)p; p += SZ;           // transposed projected v
    u16* Wqb = (u16*)p; p += (size_t)D_ * D_ * 2;  // Wqb..Wob contiguous (convert4)
    u16* Wkb = (u16*)p; p += (size_t)D_ * D_ * 2;
    u16* Wvb = (u16*)p; p += (size_t)D_ * D_ * 2;
    u16* Wob = (u16*)p; p += (size_t)D_ * D_ * 2;
    int* maskq = (int*)p; p += (size_t)B_ * L_ * 4;
    int* maskk = (int*)p; p += (size_t)B_ * L_ * 4;
    int* maskv = (int*)p; p += (size_t)B_ * L_ * 4;
    int* qmask128 = (int*)p; p += 128 * 4;   // [B][L/128]
    int* kmask128 = (int*)p; p += 128 * 4;
    int* vmask128 = (int*)p; p += 128 * 4;
    int* kmask32  = (int*)p; p += 512 * 4;   // [B][L/32]

    // 1. fused conversions + masks (q,k,v), weights, then block-skip flags
    convmask_kernel<<<B_ * L_, 256, 0, stream>>>(q, qb, maskq);
    convmask_kernel<<<B_ * L_, 256, 0, stream>>>(k, kb, maskk);
    convmask_kernel<<<B_ * L_, 256, 0, stream>>>(v, vb, maskv);
    Ptr4 wp{Wq, Wk, Wv, Wo};
    convert4_kernel<<<dim3(D_ * D_ / 4 / 256, 4), 256, 0, stream>>>(wp, Wqb);
    flags_kernel<<<896, 128, 0, stream>>>(maskq, maskk, maskv, qmask128, kmask128, vmask128, kmask32);

    // 2. projections: [16384,1024] x [1024,1024]^T  (skip all-zero row blocks)
    dim3 gp(B_ * L_ / GBM, D_ / GBN, 1);
    gemm_nt<0><<<gp, 256, 0, stream>>>(qb, Wqb, qpb, bq, nullptr, nullptr, D_, D_, 0, 0, 0, 0.f,
                                       qmask128, nullptr, nullptr, 128, 8);
    gemm_nt<0><<<gp, 256, 0, stream>>>(kb, Wkb, kpb, bk, nullptr, nullptr, D_, D_, 0, 0, 0, 0.f,
                                       kmask128, nullptr, nullptr, 128, 8);
    gemm_nt<0><<<gp, 256, 0, stream>>>(vb, Wvb, vpb, bv, nullptr, nullptr, D_, D_, 0, 0, 0, 0.f,
                                       vmask128, nullptr, nullptr, 128, 8);

    // 3. transpose vp for the PV GEMM
    transpose_k<<<dim3(D_ / 32, L_ / 32, B_), dim3(32, 8), 0, stream>>>(vpb, vpT);

    // 4. scores: S[b,i,j] = scale * qp_i . kp_j, key-masked; skip q-masked / k-masked blocks
    gemm_nt<1><<<dim3(L_ / GBM, L_ / GBN, B_), 256, 0, stream>>>(
        qpb, kpb, Sbuf, nullptr, nullptr, maskk, L_, D_,
        (long)L_ * D_, (long)L_ * D_, (long)L_ * L_ * 2, 0.03125f,
        qmask128, kmask128, nullptr, 16, 16);

    // 5. softmax rows (query-mask folded into P)
    softmax_kernel<<<B_ * L_, 256, 0, stream>>>(Sbuf, Pbuf, maskq);

    // 6. O = P @ vp  (via vpT, NT); skip q-masked row blocks and fully-masked key k-steps
    gemm_nt<2><<<dim3(L_ / GBM, D_ / GBN, B_), 256, 0, stream>>>(
        Pbuf, vpT, Obuf, nullptr, nullptr, nullptr, D_, L_,
        (long)L_ * L_, (long)D_ * L_, (long)L_ * D_ * 2, 0.f,
        qmask128, nullptr, kmask32, 16, 8);

    // 7. out-proj + bias + residual(qp); skip q-masked row blocks (acc=0 exact)
    gemm_nt<3><<<gp, 256, 0, stream>>>(Obuf, Wob, Xbuf, bo, qpb, nullptr, D_, D_, 0, 0, 0, 0.f,
                                       qmask128, nullptr, nullptr, 128, 8);

    // 8. LayerNorm -> d_out
    layernorm_kernel<<<B_ * L_, 256, 0, stream>>>(Xbuf, out);
}

// Round 3
// 635.964 us; speedup vs baseline: 1.2720x; 1.1182x over previous
//
#include <hip/hip_runtime.h>
#include <stdint.h>

typedef unsigned short u16;
typedef __attribute__((ext_vector_type(8))) short short8;
typedef __attribute__((ext_vector_type(4))) float f32x4;

#define B_ 8
#define L_ 2048
#define D_ 1024

// ---------- bf16 helpers (RNE) ----------
__device__ __forceinline__ u16 f2bf(float f) {
    unsigned int u = __float_as_uint(f);
    u = u + 0x7FFFu + ((u >> 16) & 1u);
    return (u16)(u >> 16);
}
__device__ __forceinline__ float bf2f(u16 h) {
    return __uint_as_float(((unsigned int)h) << 16);
}

// ---------- fused fp32->bf16 conversion + zero-row mask, q/k/v in one dispatch ----------
struct CM3 {
    const float* s[3];
    u16* d[3];
    int* m[3];
};
__global__ __launch_bounds__(256) void convmask3_kernel(CM3 c) {
    int sel = blockIdx.y;
    const float* x = c.s[sel];
    u16* xb = c.d[sel];
    int* mask = c.m[sel];
    long row = blockIdx.x;
    int t = threadIdx.x;
    float4 v = ((const float4*)(x + row * D_))[t];
    ushort4 o;
    o.x = f2bf(v.x); o.y = f2bf(v.y); o.z = f2bf(v.z); o.w = f2bf(v.w);
    ((ushort4*)(xb + row * D_))[t] = o;
    float s = v.x + v.y + v.z + v.w;
    #pragma unroll
    for (int off = 32; off; off >>= 1) s += __shfl_down(s, off);
    __shared__ float sh[4];
    if ((t & 63) == 0) sh[t >> 6] = s;
    __syncthreads();
    if (t == 0) {
        float tot = sh[0] + sh[1] + sh[2] + sh[3];
        mask[row] = (tot == 0.0f) ? 1 : 0;
    }
}

// ---------- all 4 weight matrices fp32->bf16 in one dispatch ----------
struct Ptr4 { const float* s0; const float* s1; const float* s2; const float* s3; };
__global__ __launch_bounds__(256) void convert4_kernel(Ptr4 p, u16* __restrict__ dst) {
    const float* srcs[4] = {p.s0, p.s1, p.s2, p.s3};
    const float* src = srcs[blockIdx.y];
    u16* d = dst + (size_t)blockIdx.y * D_ * D_;
    int i = blockIdx.x * 256 + threadIdx.x;
    float4 v = ((const float4*)src)[i];
    ushort4 o;
    o.x = f2bf(v.x); o.y = f2bf(v.y); o.z = f2bf(v.z); o.w = f2bf(v.w);
    ((ushort4*)d)[i] = o;
}

// ---------- block-group skip flags ----------
// blocks 0..127: qmask128 | 128..255: kmask128 | 256..383: vmask128 | 384..895: kmask32
__global__ __launch_bounds__(128) void flags_kernel(const int* __restrict__ mq,
                                                    const int* __restrict__ mk,
                                                    const int* __restrict__ mv,
                                                    int* __restrict__ q128,
                                                    int* __restrict__ k128,
                                                    int* __restrict__ v128,
                                                    int* __restrict__ k32) {
    int b = blockIdx.x, t = threadIdx.x;
    const int* src; int* dst; int g; int n;
    if (b < 128)      { src = mq; dst = q128; g = b;       n = 128; }
    else if (b < 256) { src = mk; dst = k128; g = b - 128; n = 128; }
    else if (b < 384) { src = mv; dst = v128; g = b - 256; n = 128; }
    else              { src = mk; dst = k32;  g = b - 384; n = 32;  }
    int val = (t < n) ? src[(long)g * n + t] : 1;
    __shared__ int sh;
    if (t == 0) sh = 1;
    __syncthreads();
    if (!val) sh = 0;
    __syncthreads();
    if (t == 0) dst[g] = sh;
}

// ---------- pack kmask32 [B][64] into per-batch uint64 of ACTIVE k-steps ----------
__global__ __launch_bounds__(512) void packbits_kernel(const int* __restrict__ k32,
                                                       unsigned long long* __restrict__ kb) {
    int t = threadIdx.x;
    int b = t >> 6;
    int bit = t & 63;
    unsigned long long m = __ballot(k32[b * 64 + bit] == 0);  // bit set = step active
    if (bit == 0) kb[b] = m;
}

// ---------- async global->LDS 16B ----------
__device__ __forceinline__ void async_cp16(const void* g, void* l) {
    __builtin_amdgcn_global_load_lds((const __attribute__((address_space(1))) unsigned int*)g,
                                     (__attribute__((address_space(3))) unsigned int*)l,
                                     16, 0, 0);
}

// ---------- per-z pointers for the merged projection dispatch (MODE 0) ----------
struct P3 {
    const u16* A[3];
    u16* C[3];
    const float* bias[3];
    const int* rs[3];
};

// ---------- NT bf16 GEMM: C[m,n] = sum_k A[m,k]*B[n,k] (+ epilogue per MODE) ----------
// MODE 0: proj (merged q/k/v via grid.z + P3) : bf16 C = acc + bias[n]
// MODE 1: scores : bf16 C = maskk[n] ? -1e30 : acc*scale
// MODE 2: PV (k-steps gated by kbits bitmask) : bf16 C = acc
// MODE 3: outproj: bf16 C = acc + bias[n] + bf2f(resid[m,n])
// LDS layout XOR-swizzled: chunk (row, kc) at slot row*4 + (kc ^ ((row>>1)&3))
// -> fragment ds_read_b128 hits each 16B granule-group exactly 2x (free, m136).
#define GBM 128
#define GBN 128
#define GBK 32

#define KSTEP(pA, pB)                                                                      \
    do {                                                                                   \
        async_cp16((pA), lA);                                                              \
        async_cp16((pA) + 64 * (long)K, lA + 2048);                                        \
        async_cp16((pB), lB);                                                              \
        async_cp16((pB) + 64 * (long)K, lB + 2048);                                        \
        __syncthreads();                                                                   \
        short8 af[4], bfr[4];                                                              \
        _Pragma("unroll")                                                                  \
        for (int i = 0; i < 4; i++)                                                        \
            af[i] = *(const short8*)&As[(mrow + i * 16) * GBK + sw];                       \
        _Pragma("unroll")                                                                  \
        for (int j = 0; j < 4; j++)                                                        \
            bfr[j] = *(const short8*)&Bs[(nrow + j * 16) * GBK + sw];                      \
        _Pragma("unroll")                                                                  \
        for (int i = 0; i < 4; i++)                                                        \
            _Pragma("unroll")                                                              \
            for (int j = 0; j < 4; j++)                                                    \
                acc[i][j] = __builtin_amdgcn_mfma_f32_16x16x32_bf16(af[i], bfr[j],         \
                                                                    acc[i][j], 0, 0, 0);   \
        __syncthreads();                                                                   \
    } while (0)

template <int MODE>
__global__ __launch_bounds__(256) void gemm_nt(const u16* __restrict__ A,
                                               const u16* __restrict__ Bm,
                                               void* __restrict__ C,
                                               const float* __restrict__ bias,
                                               const u16* __restrict__ resid,
                                               const int* __restrict__ maskk,
                                               int N, int K,
                                               long strideA, long strideB, long strideC,
                                               float scale,
                                               const int* __restrict__ rowskip,
                                               const int* __restrict__ colskip,
                                               const unsigned long long* __restrict__ kbits,
                                               int mblocks, int nblocks,
                                               P3 p3) {
    __shared__ __align__(16) u16 As[GBM * GBK];  // 8 KB
    __shared__ __align__(16) u16 Bs[GBN * GBK];  // 8 KB

    int t = threadIdx.x;
    int lane = t & 63;
    int wave = t >> 6;
    int wm = wave & 1, wn = wave >> 1;
    long m0 = (long)blockIdx.x * GBM;
    long n0 = (long)blockIdx.y * GBN;

    const u16* Ab;
    const u16* Bb;
    char* Cb;
    const float* biasp = bias;
    const int* rs;
    int rsidx;
    if (MODE == 0) {
        int z = blockIdx.z;
        Ab = p3.A[z];
        Bb = Bm + (long)z * D_ * D_;
        Cb = (char*)p3.C[z];
        biasp = p3.bias[z];
        rs = p3.rs[z];
        rsidx = blockIdx.x;
    } else {
        Ab = A + (long)blockIdx.z * strideA;
        Bb = Bm + (long)blockIdx.z * strideB;
        Cb = (char*)C + (long)blockIdx.z * strideC;
        rs = rowskip;
        rsidx = blockIdx.z * mblocks + blockIdx.x;
    }
    const int* mk = (MODE == 1) ? (maskk + (long)blockIdx.z * N) : nullptr;

    bool skipK = false;
    if (rs && rs[rsidx]) skipK = true;
    if (MODE == 1 && colskip && colskip[blockIdx.z * nblocks + blockIdx.y]) skipK = true;

    f32x4 acc[4][4] = {};

    // staging: thread t -> LDS slot t (16B). Global chunk: row=t>>2, kc=(t&3)^((t>>3)&3)
    int arow = t >> 2;
    int acol = ((t & 3) ^ ((t >> 3) & 3)) * 8;
    const u16* gA = Ab + (m0 + arow) * (long)K + acol;
    const u16* gB = Bb + (n0 + arow) * (long)K + acol;
    u16* lA = As + t * 8;
    u16* lB = Bs + t * 8;

    int mrow = wm * 64 + (lane & 15);
    int nrow = wn * 64 + (lane & 15);
    // swizzled k-chunk offset for fragment reads (invariant across i/j: 16*i>>1 ≡ 0 mod 4)
    int sw = (((lane >> 4) ^ ((lane >> 1) & 3)) * 8);

    if (!skipK) {
        if (MODE == 2) {
            unsigned long long bits = kbits[blockIdx.z];  // SGPR, loaded once
            while (bits) {
                int step = __builtin_ctzll(bits);
                bits &= bits - 1;
                const u16* pA = gA + (long)step * GBK;
                const u16* pB = gB + (long)step * GBK;
                KSTEP(pA, pB);
            }
        } else {
            for (int k0 = 0; k0 < K; k0 += GBK) {
                KSTEP(gA, gB);
                gA += GBK;
                gB += GBK;
            }
        }
    }

    long crow0 = m0 + wm * 64;
    long ccol0 = n0 + wn * 64;
    #pragma unroll
    for (int i = 0; i < 4; i++) {
        #pragma unroll
        for (int j = 0; j < 4; j++) {
            long row = crow0 + i * 16 + (lane >> 4) * 4;
            long col = ccol0 + j * 16 + (lane & 15);
            #pragma unroll
            for (int r = 0; r < 4; r++) {
                float vv = acc[i][j][r];
                long rr = row + r;
                if (MODE == 0) {
                    ((u16*)Cb)[rr * N + col] = f2bf(vv + biasp[col]);
                } else if (MODE == 1) {
                    float s = mk[col] ? -1e30f : vv * scale;
                    ((u16*)Cb)[rr * N + col] = f2bf(s);
                } else if (MODE == 2) {
                    ((u16*)Cb)[rr * N + col] = f2bf(vv);
                } else {
                    float x = vv + biasp[col] + bf2f(resid[rr * (long)N + col]);
                    ((u16*)Cb)[rr * N + col] = f2bf(x);
                }
            }
        }
    }
}

// ---------- row softmax over Lk=2048 bf16 scores, query-mask folded in ----------
__global__ __launch_bounds__(256) void softmax_kernel(const u16* __restrict__ S,
                                                      u16* __restrict__ P,
                                                      const int* __restrict__ maskq) {
    long row = blockIdx.x;
    int t = threadIdx.x;
    const u16* Sr = S + row * L_;
    u16* Pr = P + row * L_;

    if (maskq[row]) {
        short8 z = {};
        *(short8*)&Pr[t * 8] = z;
        return;
    }

    short8 raw = *(const short8*)&Sr[t * 8];
    float s[8];
    #pragma unroll
    for (int e = 0; e < 8; e++) s[e] = bf2f((u16)raw[e]);

    float mx = s[0];
    #pragma unroll
    for (int e = 1; e < 8; e++) mx = fmaxf(mx, s[e]);
    #pragma unroll
    for (int off = 32; off; off >>= 1) mx = fmaxf(mx, __shfl_down(mx, off));
    __shared__ float sh[4];
    if ((t & 63) == 0) sh[t >> 6] = mx;
    __syncthreads();
    mx = fmaxf(fmaxf(sh[0], sh[1]), fmaxf(sh[2], sh[3]));
    __syncthreads();

    float e8[8], sum = 0.f;
    #pragma unroll
    for (int e = 0; e < 8; e++) { e8[e] = __expf(s[e] - mx); sum += e8[e]; }
    #pragma unroll
    for (int off = 32; off; off >>= 1) sum += __shfl_down(sum, off);
    if ((t & 63) == 0) sh[t >> 6] = sum;
    __syncthreads();
    sum = sh[0] + sh[1] + sh[2] + sh[3];
    float inv = 1.0f / sum;

    short8 o;
    #pragma unroll
    for (int e = 0; e < 8; e++) o[e] = (short)f2bf(e8[e] * inv);
    *(short8*)&Pr[t * 8] = o;
}

// ---------- bf16 transpose per batch: dst[b][d][key] = src[b][key][d] ----------
__global__ __launch_bounds__(256) void transpose_k(const u16* __restrict__ src,
                                                   u16* __restrict__ dst) {
    __shared__ u16 tile[32][34];
    long b = blockIdx.z;
    const u16* s = src + b * (long)L_ * D_;
    u16* d = dst + b * (long)L_ * D_;
    int gx = blockIdx.x * 32;  // d
    int gy = blockIdx.y * 32;  // key
    int tx = threadIdx.x, ty = threadIdx.y;
    #pragma unroll
    for (int r = 0; r < 32; r += 8)
        tile[ty + r][tx] = s[(long)(gy + ty + r) * D_ + gx + tx];
    __syncthreads();
    #pragma unroll
    for (int r = 0; r < 32; r += 8)
        d[(long)(gx + ty + r) * L_ + gy + tx] = tile[tx][ty + r];
}

// ---------- LayerNorm (no affine), eps=1e-5; bf16 input, f32 output ----------
__global__ __launch_bounds__(256) void layernorm_kernel(const u16* __restrict__ X,
                                                        float* __restrict__ O) {
    long row = blockIdx.x;
    int t = threadIdx.x;
    ushort4 u = ((const ushort4*)(X + row * D_))[t];
    float x0 = bf2f(u.x), x1 = bf2f(u.y), x2 = bf2f(u.z), x3 = bf2f(u.w);
    float s = x0 + x1 + x2 + x3;
    #pragma unroll
    for (int off = 32; off; off >>= 1) s += __shfl_down(s, off);
    __shared__ float sh[4];
    if ((t & 63) == 0) sh[t >> 6] = s;
    __syncthreads();
    float mu = (sh[0] + sh[1] + sh[2] + sh[3]) * (1.0f / D_);
    __syncthreads();

    float d0 = x0 - mu, d1 = x1 - mu, d2 = x2 - mu, d3 = x3 - mu;
    float ss = d0 * d0 + d1 * d1 + d2 * d2 + d3 * d3;
    #pragma unroll
    for (int off = 32; off; off >>= 1) ss += __shfl_down(ss, off);
    if ((t & 63) == 0) sh[t >> 6] = ss;
    __syncthreads();
    float var = (sh[0] + sh[1] + sh[2] + sh[3]) * (1.0f / D_);
    float rs = rsqrtf(var + 1e-5f);

    float4 o;
    o.x = d0 * rs; o.y = d1 * rs; o.z = d2 * rs; o.w = d3 * rs;
    ((float4*)(O + row * D_))[t] = o;
}

extern "C" void kernel_launch(void* const* d_in, const int* in_sizes, int n_in,
                              void* d_out, int out_size, void* d_ws, size_t ws_size,
                              hipStream_t stream) {
    const float* q  = (const float*)d_in[0];
    const float* k  = (const float*)d_in[1];
    const float* v  = (const float*)d_in[2];
    const float* Wq = (const float*)d_in[3];
    const float* bq = (const float*)d_in[4];
    const float* Wk = (const float*)d_in[5];
    const float* bk = (const float*)d_in[6];
    const float* Wv = (const float*)d_in[7];
    const float* bv = (const float*)d_in[8];
    const float* Wo = (const float*)d_in[9];
    const float* bo = (const float*)d_in[10];
    float* out = (float*)d_out;

    char* ws = (char*)d_ws;
    const size_t SZ = (size_t)B_ * L_ * D_ * 2;  // 33,554,432 B (one [B,L,D] bf16)

    // Region A (4*SZ): qb,kb,vb,vpb -> then S(2*SZ) | P at +2*SZ -> then O(SZ) | X at +2*SZ
    u16* qb   = (u16*)(ws + 0 * SZ);
    u16* kb   = (u16*)(ws + 1 * SZ);
    u16* vb   = (u16*)(ws + 2 * SZ);
    u16* vpb  = (u16*)(ws + 3 * SZ);
    u16* Sbuf = (u16*)(ws + 0 * SZ);       // 2*SZ bytes, alive: scores GEMM -> softmax
    u16* Pbuf = (u16*)(ws + 2 * SZ);       // 2*SZ bytes, alive: softmax -> PV GEMM
    u16* Obuf = (u16*)(ws + 0 * SZ);       // SZ bytes,  alive: PV GEMM -> outproj
    u16* Xbuf = (u16*)(ws + 2 * SZ);       // SZ bytes,  alive: outproj -> layernorm
    char* p = ws + 4 * SZ;
    u16* qpb = (u16*)p; p += SZ;           // projected q (bf16), also residual
    u16* kpb = (u16*)p; p += SZ;
    u16* vpT = (u16*)p; p += SZ;           // transposed projected v
    u16* Wqb = (u16*)p; p += (size_t)D_ * D_ * 2;  // Wqb..Wob contiguous
    u16* Wkb = (u16*)p; p += (size_t)D_ * D_ * 2;
    u16* Wvb = (u16*)p; p += (size_t)D_ * D_ * 2;
    u16* Wob = (u16*)p; p += (size_t)D_ * D_ * 2;
    int* maskq = (int*)p; p += (size_t)B_ * L_ * 4;
    int* maskk = (int*)p; p += (size_t)B_ * L_ * 4;
    int* maskv = (int*)p; p += (size_t)B_ * L_ * 4;
    int* qmask128 = (int*)p; p += 128 * 4;   // [B][L/128]
    int* kmask128 = (int*)p; p += 128 * 4;
    int* vmask128 = (int*)p; p += 128 * 4;
    int* kmask32  = (int*)p; p += 512 * 4;   // [B][L/32]
    unsigned long long* kbits = (unsigned long long*)p; p += 8 * 8;  // [B] active-step bitmask

    P3 noP3 = {};

    // 1. fused conversions + masks (q,k,v in one dispatch), weights, flags, bitmask
    CM3 cm;
    cm.s[0] = q;  cm.s[1] = k;  cm.s[2] = v;
    cm.d[0] = qb; cm.d[1] = kb; cm.d[2] = vb;
    cm.m[0] = maskq; cm.m[1] = maskk; cm.m[2] = maskv;
    convmask3_kernel<<<dim3(B_ * L_, 3), 256, 0, stream>>>(cm);
    Ptr4 wp{Wq, Wk, Wv, Wo};
    convert4_kernel<<<dim3(D_ * D_ / 4 / 256, 4), 256, 0, stream>>>(wp, Wqb);
    flags_kernel<<<896, 128, 0, stream>>>(maskq, maskk, maskv, qmask128, kmask128, vmask128, kmask32);
    packbits_kernel<<<1, 512, 0, stream>>>(kmask32, kbits);

    // 2. merged projections: 3 x [16384,1024] x [1024,1024]^T via grid.z
    P3 pj;
    pj.A[0] = qb;  pj.A[1] = kb;  pj.A[2] = vb;
    pj.C[0] = qpb; pj.C[1] = kpb; pj.C[2] = vpb;
    pj.bias[0] = bq; pj.bias[1] = bk; pj.bias[2] = bv;
    pj.rs[0] = qmask128; pj.rs[1] = kmask128; pj.rs[2] = vmask128;
    gemm_nt<0><<<dim3(B_ * L_ / GBM, D_ / GBN, 3), 256, 0, stream>>>(
        nullptr, Wqb, nullptr, nullptr, nullptr, nullptr, D_, D_, 0, 0, 0, 0.f,
        nullptr, nullptr, nullptr, 0, 8, pj);

    // 3. transpose vp for the PV GEMM
    transpose_k<<<dim3(D_ / 32, L_ / 32, B_), dim3(32, 8), 0, stream>>>(vpb, vpT);

    // 4. scores: S[b,i,j] = scale * qp_i . kp_j, key-masked; skip q-/k-masked blocks
    gemm_nt<1><<<dim3(L_ / GBM, L_ / GBN, B_), 256, 0, stream>>>(
        qpb, kpb, Sbuf, nullptr, nullptr, maskk, L_, D_,
        (long)L_ * D_, (long)L_ * D_, (long)L_ * L_ * 2, 0.03125f,
        qmask128, kmask128, nullptr, 16, 16, noP3);

    // 5. softmax rows (query-mask folded into P)
    softmax_kernel<<<B_ * L_, 256, 0, stream>>>(Sbuf, Pbuf, maskq);

    // 6. O = P @ vp (via vpT, NT); skip q-masked row blocks; k-steps gated by kbits
    gemm_nt<2><<<dim3(L_ / GBM, D_ / GBN, B_), 256, 0, stream>>>(
        Pbuf, vpT, Obuf, nullptr, nullptr, nullptr, D_, L_,
        (long)L_ * L_, (long)D_ * L_, (long)L_ * D_ * 2, 0.f,
        qmask128, nullptr, kbits, 16, 8, noP3);

    // 7. out-proj + bias + residual(qp) -> bf16; skip q-masked row blocks (acc=0 exact)
    gemm_nt<3><<<dim3(B_ * L_ / GBM, D_ / GBN, 1), 256, 0, stream>>>(
        Obuf, Wob, Xbuf, bo, qpb, nullptr, D_, D_, 0, 0, 0, 0.f,
        qmask128, nullptr, nullptr, 128, 8, noP3);

    // 8. LayerNorm (bf16 in, f32 out) -> d_out
    layernorm_kernel<<<B_ * L_, 256, 0, stream>>>(Xbuf, out);
}

// Round 4
// 583.493 us; speedup vs baseline: 1.3864x; 1.0899x over previous
//
#include <hip/hip_runtime.h>
#include <stdint.h>

typedef unsigned short u16;
typedef __attribute__((ext_vector_type(8))) short short8;
typedef __attribute__((ext_vector_type(4))) float f32x4;

#define B_ 8
#define L_ 2048
#define D_ 1024

// ---------- bf16 helpers (RNE) ----------
__device__ __forceinline__ u16 f2bf(float f) {
    unsigned int u = __float_as_uint(f);
    u = u + 0x7FFFu + ((u >> 16) & 1u);
    return (u16)(u >> 16);
}
__device__ __forceinline__ float bf2f(u16 h) {
    return __uint_as_float(((unsigned int)h) << 16);
}

// ---------- fused fp32->bf16 conversion + zero-row mask, q/k/v in one dispatch ----------
struct CM3 {
    const float* s[3];
    u16* d[3];
    int* m[3];
};
__global__ __launch_bounds__(256) void convmask3_kernel(CM3 c) {
    int sel = blockIdx.y;
    const float* x = c.s[sel];
    u16* xb = c.d[sel];
    int* mask = c.m[sel];
    long row = blockIdx.x;
    int t = threadIdx.x;
    float4 v = ((const float4*)(x + row * D_))[t];
    ushort4 o;
    o.x = f2bf(v.x); o.y = f2bf(v.y); o.z = f2bf(v.z); o.w = f2bf(v.w);
    ((ushort4*)(xb + row * D_))[t] = o;
    float s = v.x + v.y + v.z + v.w;
    #pragma unroll
    for (int off = 32; off; off >>= 1) s += __shfl_down(s, off);
    __shared__ float sh[4];
    if ((t & 63) == 0) sh[t >> 6] = s;
    __syncthreads();
    if (t == 0) {
        float tot = sh[0] + sh[1] + sh[2] + sh[3];
        mask[row] = (tot == 0.0f) ? 1 : 0;
    }
}

// ---------- all 4 weight matrices fp32->bf16 in one dispatch ----------
struct Ptr4 { const float* s0; const float* s1; const float* s2; const float* s3; };
__global__ __launch_bounds__(256) void convert4_kernel(Ptr4 p, u16* __restrict__ dst) {
    const float* srcs[4] = {p.s0, p.s1, p.s2, p.s3};
    const float* src = srcs[blockIdx.y];
    u16* d = dst + (size_t)blockIdx.y * D_ * D_;
    int i = blockIdx.x * 256 + threadIdx.x;
    float4 v = ((const float4*)src)[i];
    ushort4 o;
    o.x = f2bf(v.x); o.y = f2bf(v.y); o.z = f2bf(v.z); o.w = f2bf(v.w);
    ((ushort4*)d)[i] = o;
}

// ---------- block-group skip flags ----------
// blocks: 0..63 q256 | 64..127 k256 | 128..191 v256 | 192..319 kmask128 | 320..831 kmask32
__global__ __launch_bounds__(256) void flags_kernel(const int* __restrict__ mq,
                                                    const int* __restrict__ mk,
                                                    const int* __restrict__ mv,
                                                    int* __restrict__ q256,
                                                    int* __restrict__ k256,
                                                    int* __restrict__ v256,
                                                    int* __restrict__ k128,
                                                    int* __restrict__ k32) {
    int b = blockIdx.x, t = threadIdx.x;
    const int* src; int* dst; int g; int n;
    if (b < 64)       { src = mq; dst = q256; g = b;       n = 256; }
    else if (b < 128) { src = mk; dst = k256; g = b - 64;  n = 256; }
    else if (b < 192) { src = mv; dst = v256; g = b - 128; n = 256; }
    else if (b < 320) { src = mk; dst = k128; g = b - 192; n = 128; }
    else              { src = mk; dst = k32;  g = b - 320; n = 32;  }
    int val = (t < n) ? src[(long)g * n + t] : 1;
    __shared__ int sh;
    if (t == 0) sh = 1;
    __syncthreads();
    if (!val) sh = 0;
    __syncthreads();
    if (t == 0) dst[g] = sh;
}

// ---------- pack kmask32 [B][64] into per-batch uint64 of ACTIVE k-steps ----------
__global__ __launch_bounds__(512) void packbits_kernel(const int* __restrict__ k32,
                                                       unsigned long long* __restrict__ kb) {
    int t = threadIdx.x;
    int b = t >> 6;
    int bit = t & 63;
    unsigned long long m = __ballot(k32[b * 64 + bit] == 0);  // bit set = step active
    if (bit == 0) kb[b] = m;
}

// ---------- async global->LDS 16B ----------
__device__ __forceinline__ void async_cp16(const void* g, void* l) {
    __builtin_amdgcn_global_load_lds((const __attribute__((address_space(1))) unsigned int*)g,
                                     (__attribute__((address_space(3))) unsigned int*)l,
                                     16, 0, 0);
}

// ---------- per-z pointers for the merged projection dispatch (MODE 0) ----------
struct P3 {
    const u16* A[3];
    u16* C[3];
    const float* bias[3];
    const int* rs[3];
};

// ---------- NT bf16 GEMM: C[m,n] = sum_k A[m,k]*B[n,k] (+ epilogue per MODE) ----------
// Block tile 256x128, 4 waves each 64 rows x 128 cols (4x8 frags of 16x16x32).
// MAC/LDS-byte ratio 2.67 vs 2.0 of the 4x4 layout -> less LDS-BW-bound.
// MODE 0: proj (merged q/k/v via grid.z + P3) : bf16 C = acc + bias[n]
// MODE 1: scores : bf16 C = maskk[n] ? -1e30 : acc*scale
// MODE 2: PV (k-steps gated by kbits bitmask) : bf16 C = acc
// MODE 3: outproj: bf16 C = acc + bias[n] + bf2f(resid[m,n])
// LDS XOR-swizzled: chunk (row, kc) at slot row*4 + (kc ^ ((row>>1)&3)) -> 2-way (free).
#define GBM 256
#define GBN 128
#define GBK 32

#define KSTEP(pA, pB)                                                                      \
    do {                                                                                   \
        async_cp16((pA), lA);                                                              \
        async_cp16((pA) + 64 * (long)K, lA + 2048);                                        \
        async_cp16((pA) + 128 * (long)K, lA + 4096);                                       \
        async_cp16((pA) + 192 * (long)K, lA + 6144);                                       \
        async_cp16((pB), lB);                                                              \
        async_cp16((pB) + 64 * (long)K, lB + 2048);                                        \
        __syncthreads();                                                                   \
        short8 af[4], bfr[8];                                                              \
        _Pragma("unroll")                                                                  \
        for (int i = 0; i < 4; i++)                                                        \
            af[i] = *(const short8*)&As[(mrow + i * 16) * GBK + sw];                       \
        _Pragma("unroll")                                                                  \
        for (int j = 0; j < 8; j++)                                                        \
            bfr[j] = *(const short8*)&Bs[((lane & 15) + j * 16) * GBK + sw];               \
        _Pragma("unroll")                                                                  \
        for (int i = 0; i < 4; i++)                                                        \
            _Pragma("unroll")                                                              \
            for (int j = 0; j < 8; j++)                                                    \
                acc[i][j] = __builtin_amdgcn_mfma_f32_16x16x32_bf16(af[i], bfr[j],         \
                                                                    acc[i][j], 0, 0, 0);   \
        __syncthreads();                                                                   \
    } while (0)

template <int MODE>
__global__ __launch_bounds__(256, 2) void gemm_nt(const u16* __restrict__ A,
                                                  const u16* __restrict__ Bm,
                                                  void* __restrict__ C,
                                                  const float* __restrict__ bias,
                                                  const u16* __restrict__ resid,
                                                  const int* __restrict__ maskk,
                                                  int N, int K,
                                                  long strideA, long strideB, long strideC,
                                                  float scale,
                                                  const int* __restrict__ rowskip,
                                                  const int* __restrict__ colskip,
                                                  const unsigned long long* __restrict__ kbits,
                                                  int mblocks, int nblocks,
                                                  P3 p3) {
    __shared__ __align__(16) u16 As[GBM * GBK];  // 16 KB
    __shared__ __align__(16) u16 Bs[GBN * GBK];  // 8 KB

    int t = threadIdx.x;
    int lane = t & 63;
    int wave = t >> 6;
    long m0 = (long)blockIdx.x * GBM;
    long n0 = (long)blockIdx.y * GBN;

    const u16* Ab;
    const u16* Bb;
    char* Cb;
    const float* biasp = bias;
    const int* rs;
    int rsidx;
    if (MODE == 0) {
        int z = blockIdx.z;
        Ab = p3.A[z];
        Bb = Bm + (long)z * D_ * D_;
        Cb = (char*)p3.C[z];
        biasp = p3.bias[z];
        rs = p3.rs[z];
        rsidx = blockIdx.x;
    } else {
        Ab = A + (long)blockIdx.z * strideA;
        Bb = Bm + (long)blockIdx.z * strideB;
        Cb = (char*)C + (long)blockIdx.z * strideC;
        rs = rowskip;
        rsidx = blockIdx.z * mblocks + blockIdx.x;
    }
    const int* mk = (MODE == 1) ? (maskk + (long)blockIdx.z * N) : nullptr;

    bool skipK = false;
    if (rs && rs[rsidx]) skipK = true;
    if (MODE == 1 && colskip && colskip[blockIdx.z * nblocks + blockIdx.y]) skipK = true;

    f32x4 acc[4][8] = {};

    // staging: thread t -> LDS slot t*8 elems (+pass offsets). Global chunk:
    // row = t>>2 (+64/128/192), kc = (t&3)^((t>>3)&3)
    int arow = t >> 2;
    int acol = ((t & 3) ^ ((t >> 3) & 3)) * 8;
    const u16* gA = Ab + (m0 + arow) * (long)K + acol;
    const u16* gB = Bb + (n0 + arow) * (long)K + acol;
    u16* lA = As + t * 8;
    u16* lB = Bs + t * 8;

    int mrow = wave * 64 + (lane & 15);
    // swizzled k-chunk offset for fragment reads (invariant across frag index:
    // 16*i>>1 ≡ 0 mod 4, 64*wave>>1 ≡ 0 mod 4)
    int sw = (((lane >> 4) ^ ((lane >> 1) & 3)) * 8);

    if (!skipK) {
        if (MODE == 2) {
            unsigned long long bits = kbits[blockIdx.z];  // SGPR, loaded once
            while (bits) {
                int step = __builtin_ctzll(bits);
                bits &= bits - 1;
                const u16* pA = gA + (long)step * GBK;
                const u16* pB = gB + (long)step * GBK;
                KSTEP(pA, pB);
            }
        } else {
            for (int k0 = 0; k0 < K; k0 += GBK) {
                KSTEP(gA, gB);
                gA += GBK;
                gB += GBK;
            }
        }
    }

    long crow0 = m0 + wave * 64;
    long ccol0 = n0;
    #pragma unroll
    for (int i = 0; i < 4; i++) {
        #pragma unroll
        for (int j = 0; j < 8; j++) {
            long row = crow0 + i * 16 + (lane >> 4) * 4;
            long col = ccol0 + j * 16 + (lane & 15);
            #pragma unroll
            for (int r = 0; r < 4; r++) {
                float vv = acc[i][j][r];
                long rr = row + r;
                if (MODE == 0) {
                    ((u16*)Cb)[rr * N + col] = f2bf(vv + biasp[col]);
                } else if (MODE == 1) {
                    float s = mk[col] ? -1e30f : vv * scale;
                    ((u16*)Cb)[rr * N + col] = f2bf(s);
                } else if (MODE == 2) {
                    ((u16*)Cb)[rr * N + col] = f2bf(vv);
                } else {
                    float x = vv + biasp[col] + bf2f(resid[rr * (long)N + col]);
                    ((u16*)Cb)[rr * N + col] = f2bf(x);
                }
            }
        }
    }
}

// ---------- row softmax over Lk=2048 bf16 scores, query-mask folded in ----------
__global__ __launch_bounds__(256) void softmax_kernel(const u16* __restrict__ S,
                                                      u16* __restrict__ P,
                                                      const int* __restrict__ maskq) {
    long row = blockIdx.x;
    int t = threadIdx.x;
    const u16* Sr = S + row * L_;
    u16* Pr = P + row * L_;

    if (maskq[row]) {
        short8 z = {};
        *(short8*)&Pr[t * 8] = z;
        return;
    }

    short8 raw = *(const short8*)&Sr[t * 8];
    float s[8];
    #pragma unroll
    for (int e = 0; e < 8; e++) s[e] = bf2f((u16)raw[e]);

    float mx = s[0];
    #pragma unroll
    for (int e = 1; e < 8; e++) mx = fmaxf(mx, s[e]);
    #pragma unroll
    for (int off = 32; off; off >>= 1) mx = fmaxf(mx, __shfl_down(mx, off));
    __shared__ float sh[4];
    if ((t & 63) == 0) sh[t >> 6] = mx;
    __syncthreads();
    mx = fmaxf(fmaxf(sh[0], sh[1]), fmaxf(sh[2], sh[3]));
    __syncthreads();

    float e8[8], sum = 0.f;
    #pragma unroll
    for (int e = 0; e < 8; e++) { e8[e] = __expf(s[e] - mx); sum += e8[e]; }
    #pragma unroll
    for (int off = 32; off; off >>= 1) sum += __shfl_down(sum, off);
    if ((t & 63) == 0) sh[t >> 6] = sum;
    __syncthreads();
    sum = sh[0] + sh[1] + sh[2] + sh[3];
    float inv = 1.0f / sum;

    short8 o;
    #pragma unroll
    for (int e = 0; e < 8; e++) o[e] = (short)f2bf(e8[e] * inv);
    *(short8*)&Pr[t * 8] = o;
}

// ---------- bf16 transpose per batch: dst[b][d][key] = src[b][key][d] ----------
__global__ __launch_bounds__(256) void transpose_k(const u16* __restrict__ src,
                                                   u16* __restrict__ dst) {
    __shared__ u16 tile[32][34];
    long b = blockIdx.z;
    const u16* s = src + b * (long)L_ * D_;
    u16* d = dst + b * (long)L_ * D_;
    int gx = blockIdx.x * 32;  // d
    int gy = blockIdx.y * 32;  // key
    int tx = threadIdx.x, ty = threadIdx.y;
    #pragma unroll
    for (int r = 0; r < 32; r += 8)
        tile[ty + r][tx] = s[(long)(gy + ty + r) * D_ + gx + tx];
    __syncthreads();
    #pragma unroll
    for (int r = 0; r < 32; r += 8)
        d[(long)(gx + ty + r) * L_ + gy + tx] = tile[tx][ty + r];
}

// ---------- LayerNorm (no affine), eps=1e-5; bf16 input, f32 output ----------
__global__ __launch_bounds__(256) void layernorm_kernel(const u16* __restrict__ X,
                                                        float* __restrict__ O) {
    long row = blockIdx.x;
    int t = threadIdx.x;
    ushort4 u = ((const ushort4*)(X + row * D_))[t];
    float x0 = bf2f(u.x), x1 = bf2f(u.y), x2 = bf2f(u.z), x3 = bf2f(u.w);
    float s = x0 + x1 + x2 + x3;
    #pragma unroll
    for (int off = 32; off; off >>= 1) s += __shfl_down(s, off);
    __shared__ float sh[4];
    if ((t & 63) == 0) sh[t >> 6] = s;
    __syncthreads();
    float mu = (sh[0] + sh[1] + sh[2] + sh[3]) * (1.0f / D_);
    __syncthreads();

    float d0 = x0 - mu, d1 = x1 - mu, d2 = x2 - mu, d3 = x3 - mu;
    float ss = d0 * d0 + d1 * d1 + d2 * d2 + d3 * d3;
    #pragma unroll
    for (int off = 32; off; off >>= 1) ss += __shfl_down(ss, off);
    if ((t & 63) == 0) sh[t >> 6] = ss;
    __syncthreads();
    float var = (sh[0] + sh[1] + sh[2] + sh[3]) * (1.0f / D_);
    float rs = rsqrtf(var + 1e-5f);

    float4 o;
    o.x = d0 * rs; o.y = d1 * rs; o.z = d2 * rs; o.w = d3 * rs;
    ((float4*)(O + row * D_))[t] = o;
}

extern "C" void kernel_launch(void* const* d_in, const int* in_sizes, int n_in,
                              void* d_out, int out_size, void* d_ws, size_t ws_size,
                              hipStream_t stream) {
    const float* q  = (const float*)d_in[0];
    const float* k  = (const float*)d_in[1];
    const float* v  = (const float*)d_in[2];
    const float* Wq = (const float*)d_in[3];
    const float* bq = (const float*)d_in[4];
    const float* Wk = (const float*)d_in[5];
    const float* bk = (const float*)d_in[6];
    const float* Wv = (const float*)d_in[7];
    const float* bv = (const float*)d_in[8];
    const float* Wo = (const float*)d_in[9];
    const float* bo = (const float*)d_in[10];
    float* out = (float*)d_out;

    char* ws = (char*)d_ws;
    const size_t SZ = (size_t)B_ * L_ * D_ * 2;  // 33,554,432 B (one [B,L,D] bf16)

    // Region A (4*SZ): qb,kb,vb,vpb -> then S(2*SZ) | P at +2*SZ -> then O(SZ) | X at +2*SZ
    u16* qb   = (u16*)(ws + 0 * SZ);
    u16* kb   = (u16*)(ws + 1 * SZ);
    u16* vb   = (u16*)(ws + 2 * SZ);
    u16* vpb  = (u16*)(ws + 3 * SZ);
    u16* Sbuf = (u16*)(ws + 0 * SZ);       // 2*SZ bytes, alive: scores GEMM -> softmax
    u16* Pbuf = (u16*)(ws + 2 * SZ);       // 2*SZ bytes, alive: softmax -> PV GEMM
    u16* Obuf = (u16*)(ws + 0 * SZ);       // SZ bytes,  alive: PV GEMM -> outproj
    u16* Xbuf = (u16*)(ws + 2 * SZ);       // SZ bytes,  alive: outproj -> layernorm
    char* p = ws + 4 * SZ;
    u16* qpb = (u16*)p; p += SZ;           // projected q (bf16), also residual
    u16* kpb = (u16*)p; p += SZ;
    u16* vpT = (u16*)p; p += SZ;           // transposed projected v
    u16* Wqb = (u16*)p; p += (size_t)D_ * D_ * 2;  // Wqb..Wob contiguous
    u16* Wkb = (u16*)p; p += (size_t)D_ * D_ * 2;
    u16* Wvb = (u16*)p; p += (size_t)D_ * D_ * 2;
    u16* Wob = (u16*)p; p += (size_t)D_ * D_ * 2;
    int* maskq = (int*)p; p += (size_t)B_ * L_ * 4;
    int* maskk = (int*)p; p += (size_t)B_ * L_ * 4;
    int* maskv = (int*)p; p += (size_t)B_ * L_ * 4;
    int* q256 = (int*)p; p += 64 * 4;        // [B*L/256]
    int* k256 = (int*)p; p += 64 * 4;
    int* v256 = (int*)p; p += 64 * 4;
    int* kmask128 = (int*)p; p += 128 * 4;   // [B][L/128]
    int* kmask32  = (int*)p; p += 512 * 4;   // [B][L/32]
    unsigned long long* kbits = (unsigned long long*)p; p += 8 * 8;  // [B] active-step bitmask

    P3 noP3 = {};

    // 1. fused conversions + masks (q,k,v in one dispatch), weights, flags, bitmask
    CM3 cm;
    cm.s[0] = q;  cm.s[1] = k;  cm.s[2] = v;
    cm.d[0] = qb; cm.d[1] = kb; cm.d[2] = vb;
    cm.m[0] = maskq; cm.m[1] = maskk; cm.m[2] = maskv;
    convmask3_kernel<<<dim3(B_ * L_, 3), 256, 0, stream>>>(cm);
    Ptr4 wp{Wq, Wk, Wv, Wo};
    convert4_kernel<<<dim3(D_ * D_ / 4 / 256, 4), 256, 0, stream>>>(wp, Wqb);
    flags_kernel<<<832, 256, 0, stream>>>(maskq, maskk, maskv, q256, k256, v256, kmask128, kmask32);
    packbits_kernel<<<1, 512, 0, stream>>>(kmask32, kbits);

    // 2. merged projections: 3 x [16384,1024] x [1024,1024]^T via grid.z
    P3 pj;
    pj.A[0] = qb;  pj.A[1] = kb;  pj.A[2] = vb;
    pj.C[0] = qpb; pj.C[1] = kpb; pj.C[2] = vpb;
    pj.bias[0] = bq; pj.bias[1] = bk; pj.bias[2] = bv;
    pj.rs[0] = q256; pj.rs[1] = k256; pj.rs[2] = v256;
    gemm_nt<0><<<dim3(B_ * L_ / GBM, D_ / GBN, 3), 256, 0, stream>>>(
        nullptr, Wqb, nullptr, nullptr, nullptr, nullptr, D_, D_, 0, 0, 0, 0.f,
        nullptr, nullptr, nullptr, 0, 8, pj);

    // 3. transpose vp for the PV GEMM
    transpose_k<<<dim3(D_ / 32, L_ / 32, B_), dim3(32, 8), 0, stream>>>(vpb, vpT);

    // 4. scores: S[b,i,j] = scale * qp_i . kp_j, key-masked; skip q-/k-masked blocks
    gemm_nt<1><<<dim3(L_ / GBM, L_ / GBN, B_), 256, 0, stream>>>(
        qpb, kpb, Sbuf, nullptr, nullptr, maskk, L_, D_,
        (long)L_ * D_, (long)L_ * D_, (long)L_ * L_ * 2, 0.03125f,
        q256, kmask128, nullptr, L_ / GBM, L_ / GBN, noP3);

    // 5. softmax rows (query-mask folded into P)
    softmax_kernel<<<B_ * L_, 256, 0, stream>>>(Sbuf, Pbuf, maskq);

    // 6. O = P @ vp (via vpT, NT); skip q-masked row blocks; k-steps gated by kbits
    gemm_nt<2><<<dim3(L_ / GBM, D_ / GBN, B_), 256, 0, stream>>>(
        Pbuf, vpT, Obuf, nullptr, nullptr, nullptr, D_, L_,
        (long)L_ * L_, (long)D_ * L_, (long)L_ * D_ * 2, 0.f,
        q256, nullptr, kbits, L_ / GBM, D_ / GBN, noP3);

    // 7. out-proj + bias + residual(qp) -> bf16; skip q-masked row blocks (acc=0 exact)
    gemm_nt<3><<<dim3(B_ * L_ / GBM, D_ / GBN, 1), 256, 0, stream>>>(
        Obuf, Wob, Xbuf, bo, qpb, nullptr, D_, D_, 0, 0, 0, 0.f,
        q256, nullptr, nullptr, B_ * L_ / GBM, D_ / GBN, noP3);

    // 8. LayerNorm (bf16 in, f32 out) -> d_out
    layernorm_kernel<<<B_ * L_, 256, 0, stream>>>(Xbuf, out);
}